// Round 2
// baseline (72.770 us; speedup 1.0000x reference)
//
#include <hip/hip_runtime.h>

#define HH 128
#define WW 128
#define NPX (HH * WW)
#define KK 10
#define PXB 16        // pixels per block (4x4 tile); pixel group = 16 contiguous lanes
#define LCAP 352      // per-tile gaussian list cap (expected ~126)
#define JMAX 22       // LCAP / 16 slots per lane
#define KEYC 6        // per-lane survivor keys (96/pixel cap, expected ~20)
#define SCAP (16 * KEYC)
#define SPAD (SCAP + 1)
#define ALPHA_MIN 5e-4f
#define RADIUS_K 3.8990f  // sqrt(2*ln(1/ALPHA_MIN))
#define NCT 64            // 8x8 coarse tiles of 16x16 px

typedef unsigned long long u64;
typedef unsigned int u32;

// ---- pass 0: coarse binning. One block per 16x16-px coarse tile scans all
// gaussians ONCE (64x2048 tests device-wide vs 1024x2048 when every fine
// block scans) and emits a packed list with fused params. Coarse rect
// contains every fine rect inside it; clamp-to-larger-rect only shrinks the
// distance -> coarse hit set is a superset of every fine tile's hit set. ----
__global__ __launch_bounds__(256) void coarse_kernel(
    const float* __restrict__ means, const float* __restrict__ rots,
    const float* __restrict__ lscales, int nG, int cstride,
    int* __restrict__ ccnt, float4* __restrict__ eb, float4* __restrict__ ep) {
  __shared__ int lcnt;
  int t = threadIdx.x;
  int lane = t & 63;
  if (t == 0) lcnt = 0;
  __syncthreads();
  int ct = blockIdx.x;
  float rx0 = (float)((ct & 7) << 4) + 0.5f, rx1 = rx0 + 15.0f;
  float ry0 = (float)((ct >> 3) << 4) + 0.5f, ry1 = ry0 + 15.0f;
  const float2* m2 = (const float2*)means;
  const float2* l2 = (const float2*)lscales;
  float4* ebt = eb + (size_t)ct * cstride;
  float4* ept = ep + (size_t)ct * cstride;
  for (int g = t; g < nG; g += 256) {
    float2 mg = m2[g];
    float2 lg = l2[g];
    float smx = __expf(fmaxf(lg.x, lg.y));
    float r = fmaf(RADIUS_K * 1.01f, smx, 0.05f);
    float cx = fminf(fmaxf(mg.x, rx0), rx1) - mg.x;
    float cy = fminf(fmaxf(mg.y, ry0), ry1) - mg.y;
    bool hit = (cx * cx + cy * cy <= r * r);
    u64 mask = __ballot(hit);
    if (mask) {                                   // wave-uniform
      int leader = __ffsll((unsigned long long)mask) - 1;
      int base;
      if (lane == leader) base = atomicAdd(&lcnt, __popcll(mask));
      base = __shfl(base, leader);
      if (hit) {
        int idx = base + __popcll(mask & ((1ull << lane) - 1ull));
        // idx < lcnt_final <= nG <= cstride: no overflow possible
        float th = rots[g];
        float s = __sinf(th), c = __cosf(th);
        float ivx = __expf(-2.0f * lg.x);
        float ivy = __expf(-2.0f * lg.y);
        ebt[idx] = make_float4(mg.x, mg.y, r * r, __int_as_float(g));
        ept[idx] = make_float4(c * c * ivx + s * s * ivy,
                               2.0f * (c * s * (ivx - ivy)),
                               s * s * ivx + c * c * ivy, mg.x);
      }
    }
  }
  __syncthreads();
  if (t == 0) ccnt[ct] = lcnt;
}

// One block = one 4x4-pixel tile; 4 waves; each pixel owned by 16 contiguous
// lanes of one wave -> all post-filter steps are wave-synchronous (no barriers).
template <int NGC, bool PRE>
__global__ __launch_bounds__(256) void splat_kernel(
    const float* __restrict__ means, const float* __restrict__ rots,
    const float* __restrict__ lscales, const float* __restrict__ cols,
    const int* __restrict__ ccnt, const float4* __restrict__ eb,
    const float4* __restrict__ ep, int cstride,
    int nG_rt, float* __restrict__ out) {
  const int nG = NGC > 0 ? NGC : nG_rt;
  __shared__ float4 sA[LCAP];           // (a, 2b, c, mean_x)
  __shared__ float  sMy[LCAP];
  __shared__ int    glist[LCAP];
  __shared__ float2 sbuf[PXB][SPAD];    // (alpha, id-bits)
  __shared__ float2 wbuf[PXB][KK];      // winners by rank
  __shared__ int    lcnt;

  int t = threadIdx.x;
  int lane = t & 63;
  int pl  = t >> 4;   // pixel within tile (wave w owns pixels 4w..4w+3)
  int tsl = t & 15;   // lane within pixel group
  int tile = blockIdx.x;
  int x0 = (tile & 31) << 2, y0 = (tile >> 5) << 2;
  int x = x0 | (pl & 3), y = y0 | (pl >> 2);
  float px = (float)x + 0.5f, py = (float)y + 0.5f;

  if (t == 0) lcnt = 0;
  __syncthreads();

  // ---- phase 1: fine filter from the coarse list (~250 entries -> 1-2
  // rounds instead of 8 over all gaussians), ballot-aggregated compaction.
  // Same fine test as before -> survivor set identical; order may differ but
  // all downstream selection is a total order on (alpha, id) -> bit-exact. ----
  float rx0 = (float)x0 + 0.5f, rx1 = (float)x0 + 3.5f;
  float ry0 = (float)y0 + 0.5f, ry1 = (float)y0 + 3.5f;
  if (PRE) {
    int ct = ((y0 >> 4) << 3) | (x0 >> 4);
    int cc = ccnt[ct];                  // block-uniform
    const float4* ebt = eb + (size_t)ct * cstride;
    const float4* ept = ep + (size_t)ct * cstride;
    for (int i = t; i < cc; i += 256) {
      float4 b = ebt[i];
      float cx = fminf(fmaxf(b.x, rx0), rx1) - b.x;
      float cy = fminf(fmaxf(b.y, ry0), ry1) - b.y;
      bool hit = (cx * cx + cy * cy <= b.z);
      u64 mask = __ballot(hit);
      if (mask) {                                 // wave-uniform
        int leader = __ffsll((unsigned long long)mask) - 1;
        int base;
        if (lane == leader) base = atomicAdd(&lcnt, __popcll(mask));
        base = __shfl(base, leader);
        if (hit) {
          int idx = base + __popcll(mask & ((1ull << lane) - 1ull));
          if (idx < LCAP) {
            sA[idx] = ept[i];
            sMy[idx] = b.y;
            glist[idx] = __float_as_int(b.w);
          }
        }
      }
    }
  } else {
    const float2* m2 = (const float2*)means;
    const float2* l2 = (const float2*)lscales;
    for (int g = t; g < nG; g += 256) {
      float2 mg = m2[g];
      float2 lg = l2[g];
      float smx = __expf(fmaxf(lg.x, lg.y));
      float r = fmaf(RADIUS_K * 1.01f, smx, 0.05f);
      float cx = fminf(fmaxf(mg.x, rx0), rx1) - mg.x;
      float cy = fminf(fmaxf(mg.y, ry0), ry1) - mg.y;
      bool hit = (cx * cx + cy * cy <= r * r);
      u64 mask = __ballot(hit);
      if (mask) {
        int leader = __ffsll((unsigned long long)mask) - 1;
        int base;
        if (lane == leader) base = atomicAdd(&lcnt, __popcll(mask));
        base = __shfl(base, leader);
        if (hit) {
          int idx = base + __popcll(mask & ((1ull << lane) - 1ull));
          if (idx < LCAP) {
            float th = rots[g];
            float s = __sinf(th), c = __cosf(th);
            float ivx = __expf(-2.0f * lg.x);
            float ivy = __expf(-2.0f * lg.y);
            sA[idx] = make_float4(c * c * ivx + s * s * ivy,
                                  2.0f * (c * s * (ivx - ivy)),
                                  s * s * ivx + c * c * ivy, mg.x);
            sMy[idx] = mg.y;
            glist[idx] = g;
          }
        }
      }
    }
  }
  __syncthreads();                                // last barrier
  int cnt = min(lcnt, LCAP);
  int jcnt = (cnt + 15) >> 4;  // BLOCK-uniform -> dead unrolled iterations
                               // skip via scalar branch (s_cbranch)

  // ---- phase 2: eval into registers ----
  float ra[JMAX];
  float mymax = 0.0f;
#pragma unroll
  for (int j = 0; j < JMAX; ++j) {
    float a = 0.0f;
    if (j < jcnt) {
      int i = tsl + (j << 4);
      if (i < cnt) {
        float4 q0 = sA[i];
        float dx = px - q0.w, dy = py - sMy[i];
        float q = fmaf(dx, fmaf(q0.y, dy, q0.x * dx), q0.z * dy * dy);
        a = __expf(-0.5f * q);
      }
    }
    ra[j] = a;
    mymax = fmaxf(mymax, a);
  }

  // ---- tau = 10th largest of the 16 lane maxes (sound lower bound on the
  // pixel's true 10th: distinct lanes -> distinct candidates). Bitonic sort
  // across the 16-lane group; tau only gates a SUPERSET of the top-10, so
  // list-order changes upstream cannot change the final top-10. ----
  float v = mymax;
#pragma unroll
  for (int k = 2; k <= 16; k <<= 1) {
#pragma unroll
    for (int j = k >> 1; j >= 1; j >>= 1) {
      float o = __shfl_xor(v, j, 16);
      bool keepMax = (((tsl & k) == 0) == ((tsl & j) == 0));
      v = keepMax ? fmaxf(v, o) : fminf(v, o);
    }
  }
  float tau = fmaxf(__shfl(v, 9, 16), ALPHA_MIN);

  // ---- gated push via ballot compaction (no atomics, same-wave LDS) ----
  int cpx = 0;                 // group-uniform running count
  int grp = lane >> 4;
#pragma unroll
  for (int j = 0; j < JMAX; ++j) {
    if (j < jcnt) {
      bool s = ra[j] >= tau;   // implies slot valid (else ra==0 < tau)
      u64 mask = __ballot(s);
      u32 sub = (u32)((mask >> (grp * 16)) & 0xFFFFull);
      if (s) {
        int idx = cpx + __popc(sub & ((1u << tsl) - 1u));
        if (idx < SCAP)
          sbuf[pl][idx] = make_float2(ra[j], __int_as_float(glist[tsl + (j << 4)]));
      }
      cpx += __popc(sub);
    }
  }
  int scp = min(cpx, SCAP);
  int nw = min(scp, KK);

  // ---- rank-based top-10: key = (alpha_bits<<32)|~id (unique; desc key ==
  // alpha desc, id asc == exact jax.lax.top_k order). rank = #keys greater;
  // ranks distinct 0..scp-1 -> winner rank r IS the r-th extracted max.
  // Same-wave DS is in-order: sbuf reads < wbuf writes < wbuf reads. ----
#pragma unroll
  for (int c = 0; c < KEYC; ++c) {
    if ((c << 4) < scp) {      // group-uniform; usually only c=0 (scp~20)
      int i = tsl + (c << 4);
      u64 kc = 0;
      if (i < scp) {
        float2 e = sbuf[pl][i];
        kc = ((u64)__float_as_uint(e.x) << 32) | (u32)(~(u32)__float_as_int(e.y));
      }
      int rk = 0;
      for (int s2 = 0; s2 < scp; ++s2) {
        float2 e2 = sbuf[pl][s2];                 // broadcast read
        u64 ks2 = ((u64)__float_as_uint(e2.x) << 32) |
                  (u32)(~(u32)__float_as_int(e2.y));
        rk += (kc < ks2) ? 1 : 0;
      }
      if (kc != 0 && rk < KK)
        wbuf[pl][rk] = make_float2(__uint_as_float((u32)(kc >> 32)),
                                   __int_as_float((int)(~(u32)kc)));
    }
  }

  float my_alpha = 0.0f;
  int my_id = 0;
  if (tsl < nw) {              // exactly nw winners wrote ranks 0..nw-1
    float2 e = wbuf[pl][tsl];
    my_alpha = e.x;
    my_id = __float_as_int(e.y);
  }

  // ---- composite: exclusive prefix product of (1-alpha) + butterfly sum ----
  float T = 1.0f - my_alpha;           // lanes >= nw: alpha=0 -> om=1
#pragma unroll
  for (int d = 1; d < 16; d <<= 1) {
    float u = __shfl_up(T, d, 16);
    if (tsl >= d) T *= u;
  }
  float ex = __shfl_up(T, 1, 16);
  if (tsl == 0) ex = 1.0f;
  float w = my_alpha * ex;
  float cr = 0.0f, cg = 0.0f, cb = 0.0f;
  if (my_alpha > 0.0f) {
    cr = w * cols[3 * my_id + 0];
    cg = w * cols[3 * my_id + 1];
    cb = w * cols[3 * my_id + 2];
  }
#pragma unroll
  for (int d = 1; d < 16; d <<= 1) {
    cr += __shfl_xor(cr, d);
    cg += __shfl_xor(cg, d);
    cb += __shfl_xor(cb, d);
  }
  int p = y * WW + x;
  if (tsl < 3) out[3 * p + tsl] = (tsl == 0) ? cr : ((tsl == 1) ? cg : cb);
}

extern "C" void kernel_launch(void* const* d_in, const int* in_sizes, int n_in,
                              void* d_out, int out_size, void* d_ws, size_t ws_size,
                              hipStream_t stream) {
  const float* means   = (const float*)d_in[0];
  const float* rots    = (const float*)d_in[1];
  const float* lscales = (const float*)d_in[2];
  const float* cols    = (const float*)d_in[3];
  float* out = (float*)d_out;
  int nG = in_sizes[1];  // rotations: one per gaussian

  int cstride = nG;      // per-coarse-tile list capacity: overflow impossible
  size_t need = 256 + (size_t)NCT * cstride * sizeof(float4) * 2;
  bool pre = (d_ws != nullptr) && (ws_size >= need);
  int* ccnt = (int*)d_ws;
  float4* eb = (float4*)((char*)d_ws + 256);
  float4* ep = eb + (size_t)NCT * cstride;

  if (pre)
    coarse_kernel<<<NCT, 256, 0, stream>>>(means, rots, lscales, nG, cstride,
                                           ccnt, eb, ep);

  if (nG == 2048) {
    if (pre)
      splat_kernel<2048, true><<<NPX / PXB, 256, 0, stream>>>(
          means, rots, lscales, cols, ccnt, eb, ep, cstride, nG, out);
    else
      splat_kernel<2048, false><<<NPX / PXB, 256, 0, stream>>>(
          means, rots, lscales, cols, nullptr, nullptr, nullptr, 0, nG, out);
  } else {
    if (pre)
      splat_kernel<0, true><<<NPX / PXB, 256, 0, stream>>>(
          means, rots, lscales, cols, ccnt, eb, ep, cstride, nG, out);
    else
      splat_kernel<0, false><<<NPX / PXB, 256, 0, stream>>>(
          means, rots, lscales, cols, nullptr, nullptr, nullptr, 0, nG, out);
  }
}

// Round 4
// 69.751 us; speedup vs baseline: 1.0433x; 1.0433x over previous
//
#include <hip/hip_runtime.h>

#define HH 128
#define WW 128
#define NPX (HH * WW)
#define KK 10
#define PXB 16        // pixels per block (4x4 tile); pixel group = 16 contiguous lanes
#define LCAP 352      // per-tile gaussian list cap (expected ~126)
#define JMAX 22       // LCAP / 16 slots per lane
#define KEYC 6        // per-lane survivor keys (96/pixel cap, expected ~20)
#define SCAP (16 * KEYC)
#define SPAD (SCAP + 1)
#define ALPHA_MIN 5e-4f
#define RADIUS_K 3.8990f  // sqrt(2*ln(1/ALPHA_MIN))

typedef unsigned long long u64;
typedef unsigned int u32;

// ---- pass 0: per-gaussian derived params, computed ONCE (8 blocks, ~1us).
// bbox4 = (mx, my, r^2, unused) for the filter test; prm4 = (a, 2b, c, mx)
// for eval. Serial depth deliberately minimal (R2 lesson: a heavier pre-pass
// regresses 1:1 even when it saves splat-side work). ----
__global__ __launch_bounds__(256) void precompute_kernel(
    const float* __restrict__ means, const float* __restrict__ rots,
    const float* __restrict__ lscales, int nG,
    float4* __restrict__ bbox4, float4* __restrict__ prm4) {
  int g = blockIdx.x * blockDim.x + threadIdx.x;
  if (g >= nG) return;
  const float2* m2 = (const float2*)means;
  const float2* l2 = (const float2*)lscales;
  float2 mg = m2[g];
  float2 lg = l2[g];
  float smx = __expf(fmaxf(lg.x, lg.y));
  float r = fmaf(RADIUS_K * 1.01f, smx, 0.05f);
  float th = rots[g];
  float s = __sinf(th), c = __cosf(th);
  float ivx = __expf(-2.0f * lg.x);
  float ivy = __expf(-2.0f * lg.y);
  bbox4[g] = make_float4(mg.x, mg.y, r * r, 0.0f);
  prm4[g] = make_float4(c * c * ivx + s * s * ivy,   // (a, 2b, c, mx)
                        2.0f * (c * s * (ivx - ivy)),
                        s * s * ivx + c * c * ivy, mg.x);
}

// One block = one 4x4-pixel tile; 4 waves; each pixel owned by 16 contiguous
// lanes of one wave -> all post-filter steps are wave-synchronous (no barriers).
template <int NGC, bool PRE>
__global__ __launch_bounds__(256) void splat_kernel(
    const float* __restrict__ means, const float* __restrict__ rots,
    const float* __restrict__ lscales, const float* __restrict__ cols,
    const float4* __restrict__ bbox4, const float4* __restrict__ prm4,
    int nG_rt, float* __restrict__ out) {
  const int nG = NGC > 0 ? NGC : nG_rt;
  __shared__ float4 sA[LCAP];           // (a, 2b, c, mean_x)
  __shared__ float  sMy[LCAP];
  __shared__ int    glist[LCAP];
  __shared__ float2 sbuf[PXB][SPAD];    // (alpha, id-bits)
  __shared__ float2 wbuf[PXB][KK];      // winners by rank
  __shared__ int    lcnt;

  int t = threadIdx.x;
  int lane = t & 63;
  int pl  = t >> 4;   // pixel within tile (wave w owns pixels 4w..4w+3)
  int tsl = t & 15;   // lane within pixel group
  int tile = blockIdx.x;
  int x0 = (tile & 31) << 2, y0 = (tile >> 5) << 2;
  int x = x0 | (pl & 3), y = y0 | (pl >> 2);
  float px = (float)x + 0.5f, py = (float)y + 0.5f;

  if (t == 0) lcnt = 0;
  __syncthreads();

  // ---- phase 1: conservative bbox filter, ballot-aggregated compaction.
  // alpha >= ALPHA_MIN implies |d| <= RADIUS_K*s_max; circle-vs-rect with
  // fp32 margin never drops a contributor. ----
  float rx0 = (float)x0 + 0.5f, rx1 = (float)x0 + 3.5f;
  float ry0 = (float)y0 + 0.5f, ry1 = (float)y0 + 3.5f;
  if (PRE && NGC > 0) {
    // Compile-time trip count: PREFETCH all bbox loads into registers, THEN
    // run the ballot/atomic chain back-to-back. R1 interleaved load->ballot
    // per round, paying ~L2 latency x rounds on the block critical path.
    // FR clamped >=1 so the NGC=0 instantiation stays well-formed (the whole
    // branch is runtime-dead there).
    constexpr int FR = ((NGC > 0 ? NGC : 1) + 255) / 256;
    float4 bb[FR];
#pragma unroll
    for (int j = 0; j < FR; ++j) {
      int g = t + (j << 8);
      bb[j] = (g < NGC) ? bbox4[g] : make_float4(-1e30f, -1e30f, 0.0f, 0.0f);
    }
#pragma unroll
    for (int j = 0; j < FR; ++j) {
      float4 b = bb[j];
      float cx = fminf(fmaxf(b.x, rx0), rx1) - b.x;
      float cy = fminf(fmaxf(b.y, ry0), ry1) - b.y;
      bool hit = (cx * cx + cy * cy <= b.z);
      u64 mask = __ballot(hit);
      if (mask) {                                 // wave-uniform
        int leader = __ffsll((unsigned long long)mask) - 1;
        int base;
        if (lane == leader) base = atomicAdd(&lcnt, __popcll(mask));
        base = __shfl(base, leader);
        if (hit) {
          int idx = base + __popcll(mask & ((1ull << lane) - 1ull));
          if (idx < LCAP) {
            int g = t + (j << 8);
            sA[idx] = prm4[g];                    // gathered; off critical path
            sMy[idx] = b.y;
            glist[idx] = g;
          }
        }
      }
    }
  } else if (PRE) {
    for (int g = t; g < nG; g += 256) {
      float4 b = bbox4[g];
      float cx = fminf(fmaxf(b.x, rx0), rx1) - b.x;
      float cy = fminf(fmaxf(b.y, ry0), ry1) - b.y;
      bool hit = (cx * cx + cy * cy <= b.z);
      u64 mask = __ballot(hit);
      if (mask) {
        int leader = __ffsll((unsigned long long)mask) - 1;
        int base;
        if (lane == leader) base = atomicAdd(&lcnt, __popcll(mask));
        base = __shfl(base, leader);
        if (hit) {
          int idx = base + __popcll(mask & ((1ull << lane) - 1ull));
          if (idx < LCAP) {
            sA[idx] = prm4[g];
            sMy[idx] = b.y;
            glist[idx] = g;
          }
        }
      }
    }
  } else {
    const float2* m2 = (const float2*)means;
    const float2* l2 = (const float2*)lscales;
    for (int g = t; g < nG; g += 256) {
      float2 mg = m2[g];
      float2 lg = l2[g];
      float smx = __expf(fmaxf(lg.x, lg.y));
      float r = fmaf(RADIUS_K * 1.01f, smx, 0.05f);
      float cx = fminf(fmaxf(mg.x, rx0), rx1) - mg.x;
      float cy = fminf(fmaxf(mg.y, ry0), ry1) - mg.y;
      bool hit = (cx * cx + cy * cy <= r * r);
      u64 mask = __ballot(hit);
      if (mask) {
        int leader = __ffsll((unsigned long long)mask) - 1;
        int base;
        if (lane == leader) base = atomicAdd(&lcnt, __popcll(mask));
        base = __shfl(base, leader);
        if (hit) {
          int idx = base + __popcll(mask & ((1ull << lane) - 1ull));
          if (idx < LCAP) {
            float th = rots[g];
            float s = __sinf(th), c = __cosf(th);
            float ivx = __expf(-2.0f * lg.x);
            float ivy = __expf(-2.0f * lg.y);
            sA[idx] = make_float4(c * c * ivx + s * s * ivy,
                                  2.0f * (c * s * (ivx - ivy)),
                                  s * s * ivx + c * c * ivy, mg.x);
            sMy[idx] = mg.y;
            glist[idx] = g;
          }
        }
      }
    }
  }
  __syncthreads();                                // last barrier
  int cnt = min(lcnt, LCAP);
  int jcnt = (cnt + 15) >> 4;  // BLOCK-uniform -> dead unrolled iterations
                               // skip via scalar branch (s_cbranch)

  // ---- phase 2: eval into registers ----
  float ra[JMAX];
  float mymax = 0.0f;
#pragma unroll
  for (int j = 0; j < JMAX; ++j) {
    float a = 0.0f;
    if (j < jcnt) {
      int i = tsl + (j << 4);
      if (i < cnt) {
        float4 q0 = sA[i];
        float dx = px - q0.w, dy = py - sMy[i];
        float q = fmaf(dx, fmaf(q0.y, dy, q0.x * dx), q0.z * dy * dy);
        a = __expf(-0.5f * q);
      }
    }
    ra[j] = a;
    mymax = fmaxf(mymax, a);
  }

  // ---- tau = 10th largest of the 16 lane maxes (sound lower bound on the
  // pixel's true 10th: distinct lanes -> distinct candidates). Bitonic sort
  // across the 16-lane group; tau only gates a SUPERSET of the top-10, so
  // list-order changes upstream cannot change the final top-10. ----
  float v = mymax;
#pragma unroll
  for (int k = 2; k <= 16; k <<= 1) {
#pragma unroll
    for (int j = k >> 1; j >= 1; j >>= 1) {
      float o = __shfl_xor(v, j, 16);
      bool keepMax = (((tsl & k) == 0) == ((tsl & j) == 0));
      v = keepMax ? fmaxf(v, o) : fminf(v, o);
    }
  }
  float tau = fmaxf(__shfl(v, 9, 16), ALPHA_MIN);

  // ---- gated push via ballot compaction (no atomics, same-wave LDS) ----
  int cpx = 0;                 // group-uniform running count
  int grp = lane >> 4;
#pragma unroll
  for (int j = 0; j < JMAX; ++j) {
    if (j < jcnt) {
      bool s = ra[j] >= tau;   // implies slot valid (else ra==0 < tau)
      u64 mask = __ballot(s);
      u32 sub = (u32)((mask >> (grp * 16)) & 0xFFFFull);
      if (s) {
        int idx = cpx + __popc(sub & ((1u << tsl) - 1u));
        if (idx < SCAP)
          sbuf[pl][idx] = make_float2(ra[j], __int_as_float(glist[tsl + (j << 4)]));
      }
      cpx += __popc(sub);
    }
  }
  int scp = min(cpx, SCAP);
  int nw = min(scp, KK);

  // ---- rank-based top-10: key = (alpha_bits<<32)|~id (unique; desc key ==
  // alpha desc, id asc == exact jax.lax.top_k order). rank = #keys greater;
  // ranks distinct 0..scp-1 -> winner rank r IS the r-th extracted max.
  // Same-wave DS is in-order: sbuf reads < wbuf writes < wbuf reads. ----
#pragma unroll
  for (int c = 0; c < KEYC; ++c) {
    if ((c << 4) < scp) {      // group-uniform; usually only c=0 (scp~20)
      int i = tsl + (c << 4);
      u64 kc = 0;
      if (i < scp) {
        float2 e = sbuf[pl][i];
        kc = ((u64)__float_as_uint(e.x) << 32) | (u32)(~(u32)__float_as_int(e.y));
      }
      int rk = 0;
      for (int s2 = 0; s2 < scp; ++s2) {
        float2 e2 = sbuf[pl][s2];                 // broadcast read
        u64 ks2 = ((u64)__float_as_uint(e2.x) << 32) |
                  (u32)(~(u32)__float_as_int(e2.y));
        rk += (kc < ks2) ? 1 : 0;
      }
      if (kc != 0 && rk < KK)
        wbuf[pl][rk] = make_float2(__uint_as_float((u32)(kc >> 32)),
                                   __int_as_float((int)(~(u32)kc)));
    }
  }

  float my_alpha = 0.0f;
  int my_id = 0;
  if (tsl < nw) {              // exactly nw winners wrote ranks 0..nw-1
    float2 e = wbuf[pl][tsl];
    my_alpha = e.x;
    my_id = __float_as_int(e.y);
  }

  // ---- composite: exclusive prefix product of (1-alpha) + butterfly sum ----
  float T = 1.0f - my_alpha;           // lanes >= nw: alpha=0 -> om=1
#pragma unroll
  for (int d = 1; d < 16; d <<= 1) {
    float u = __shfl_up(T, d, 16);
    if (tsl >= d) T *= u;
  }
  float ex = __shfl_up(T, 1, 16);
  if (tsl == 0) ex = 1.0f;
  float w = my_alpha * ex;
  float cr = 0.0f, cg = 0.0f, cb = 0.0f;
  if (my_alpha > 0.0f) {
    cr = w * cols[3 * my_id + 0];
    cg = w * cols[3 * my_id + 1];
    cb = w * cols[3 * my_id + 2];
  }
#pragma unroll
  for (int d = 1; d < 16; d <<= 1) {
    cr += __shfl_xor(cr, d);
    cg += __shfl_xor(cg, d);
    cb += __shfl_xor(cb, d);
  }
  int p = y * WW + x;
  if (tsl < 3) out[3 * p + tsl] = (tsl == 0) ? cr : ((tsl == 1) ? cg : cb);
}

extern "C" void kernel_launch(void* const* d_in, const int* in_sizes, int n_in,
                              void* d_out, int out_size, void* d_ws, size_t ws_size,
                              hipStream_t stream) {
  const float* means   = (const float*)d_in[0];
  const float* rots    = (const float*)d_in[1];
  const float* lscales = (const float*)d_in[2];
  const float* cols    = (const float*)d_in[3];
  float* out = (float*)d_out;
  int nG = in_sizes[1];  // rotations: one per gaussian

  size_t need = (size_t)nG * sizeof(float4) * 2;
  bool pre = (d_ws != nullptr) && (ws_size >= need);
  float4* bbox4 = (float4*)d_ws;
  float4* prm4 = (float4*)((char*)d_ws + (size_t)nG * sizeof(float4));

  if (pre)
    precompute_kernel<<<(nG + 255) / 256, 256, 0, stream>>>(means, rots,
                                                            lscales, nG,
                                                            bbox4, prm4);

  if (nG == 2048) {
    if (pre)
      splat_kernel<2048, true><<<NPX / PXB, 256, 0, stream>>>(
          means, rots, lscales, cols, bbox4, prm4, nG, out);
    else
      splat_kernel<2048, false><<<NPX / PXB, 256, 0, stream>>>(
          means, rots, lscales, cols, nullptr, nullptr, nG, out);
  } else {
    if (pre)
      splat_kernel<0, true><<<NPX / PXB, 256, 0, stream>>>(
          means, rots, lscales, cols, bbox4, prm4, nG, out);
    else
      splat_kernel<0, false><<<NPX / PXB, 256, 0, stream>>>(
          means, rots, lscales, cols, nullptr, nullptr, nG, out);
  }
}

// Round 5
// 68.221 us; speedup vs baseline: 1.0667x; 1.0224x over previous
//
#include <hip/hip_runtime.h>

#define HH 128
#define WW 128
#define NPX (HH * WW)
#define KK 10
#define PXB 16        // pixels per block (4x4 tile); pixel group = 16 contiguous lanes
#define LCAP 352      // per-tile gaussian list cap (expected ~126)
#define JMAX 22       // LCAP / 16 slots per lane
#define KEYC 6        // per-lane survivor keys (96/pixel cap, expected ~20)
#define SCAP (16 * KEYC)
#define SPAD (SCAP + 1)
#define ALPHA_MIN 5e-4f
#define RADIUS_K 3.8990f  // sqrt(2*ln(1/ALPHA_MIN))

typedef unsigned long long u64;
typedef unsigned int u32;

// Single kernel: the former 8-block precompute pre-pass was pure serial
// latency (~2.5-3us: 1.5% device utilization + a graph-node launch gap).
// Its work now runs INSIDE splat: the filter tests raw inputs (phase 1a,
// +1 expf per round), and per-survivor trig runs dense post-compaction
// (phase 1b, ~126 threads, one round). R2/R4 lesson: parallel redundancy
// inside the 1024-block kernel is nearly free; serial pre-pass depth is not.
//
// One block = one 4x4-pixel tile; 4 waves; each pixel owned by 16 contiguous
// lanes of one wave -> all post-filter steps are wave-synchronous.
template <int NGC>
__global__ __launch_bounds__(256) void splat_kernel(
    const float* __restrict__ means, const float* __restrict__ rots,
    const float* __restrict__ lscales, const float* __restrict__ cols,
    int nG_rt, float* __restrict__ out) {
  const int nG = NGC > 0 ? NGC : nG_rt;
  __shared__ float4 sA[LCAP];           // (a, 2b, c, mean_x)
  __shared__ float  sMy[LCAP];
  __shared__ int    glist[LCAP];
  __shared__ float2 sbuf[PXB][SPAD];    // (alpha, id-bits)
  __shared__ float2 wbuf[PXB][KK];      // winners by rank
  __shared__ int    lcnt;

  int t = threadIdx.x;
  int lane = t & 63;
  int pl  = t >> 4;   // pixel within tile (wave w owns pixels 4w..4w+3)
  int tsl = t & 15;   // lane within pixel group
  int tile = blockIdx.x;
  int x0 = (tile & 31) << 2, y0 = (tile >> 5) << 2;
  int x = x0 | (pl & 3), y = y0 | (pl >> 2);
  float px = (float)x + 0.5f, py = (float)y + 0.5f;

  if (t == 0) lcnt = 0;
  __syncthreads();

  // ---- phase 1a: conservative bbox filter from RAW inputs, register-
  // prefetched; ballot-aggregated compaction writes only glist/sMy (no trig
  // in the divergent hit path). alpha >= ALPHA_MIN implies |d| <=
  // RADIUS_K*s_max; circle-vs-rect with fp32 margin never drops a
  // contributor. Same expressions as the old precompute -> same bits. ----
  const float2* m2 = (const float2*)means;
  const float2* l2 = (const float2*)lscales;
  float rx0 = (float)x0 + 0.5f, rx1 = (float)x0 + 3.5f;
  float ry0 = (float)y0 + 0.5f, ry1 = (float)y0 + 3.5f;
  if (NGC > 0) {
    constexpr int FR = ((NGC > 0 ? NGC : 1) + 255) / 256;
    float2 mg[FR], lg[FR];
#pragma unroll
    for (int j = 0; j < FR; ++j) {
      int g = t + (j << 8);
      bool v = g < NGC;
      mg[j] = v ? m2[g] : make_float2(-1e30f, -1e30f);
      lg[j] = v ? l2[g] : make_float2(0.0f, 0.0f);
    }
#pragma unroll
    for (int j = 0; j < FR; ++j) {
      float smx = __expf(fmaxf(lg[j].x, lg[j].y));
      float r = fmaf(RADIUS_K * 1.01f, smx, 0.05f);
      float cx = fminf(fmaxf(mg[j].x, rx0), rx1) - mg[j].x;
      float cy = fminf(fmaxf(mg[j].y, ry0), ry1) - mg[j].y;
      bool hit = (cx * cx + cy * cy <= r * r);
      u64 mask = __ballot(hit);
      if (mask) {                                 // wave-uniform
        int leader = __ffsll((unsigned long long)mask) - 1;
        int base;
        if (lane == leader) base = atomicAdd(&lcnt, __popcll(mask));
        base = __shfl(base, leader);
        if (hit) {
          int idx = base + __popcll(mask & ((1ull << lane) - 1ull));
          if (idx < LCAP) {
            sMy[idx] = mg[j].y;
            glist[idx] = t + (j << 8);
          }
        }
      }
    }
  } else {
    for (int g = t; g < nG; g += 256) {
      float2 mgj = m2[g];
      float2 lgj = l2[g];
      float smx = __expf(fmaxf(lgj.x, lgj.y));
      float r = fmaf(RADIUS_K * 1.01f, smx, 0.05f);
      float cx = fminf(fmaxf(mgj.x, rx0), rx1) - mgj.x;
      float cy = fminf(fmaxf(mgj.y, ry0), ry1) - mgj.y;
      bool hit = (cx * cx + cy * cy <= r * r);
      u64 mask = __ballot(hit);
      if (mask) {
        int leader = __ffsll((unsigned long long)mask) - 1;
        int base;
        if (lane == leader) base = atomicAdd(&lcnt, __popcll(mask));
        base = __shfl(base, leader);
        if (hit) {
          int idx = base + __popcll(mask & ((1ull << lane) - 1ull));
          if (idx < LCAP) {
            sMy[idx] = mgj.y;
            glist[idx] = g;
          }
        }
      }
    }
  }
  __syncthreads();
  int cnt = min(lcnt, LCAP);

  // ---- phase 1b: dense per-survivor param build (~cnt=126 threads, one
  // round, full lane utilization; gathered loads are L2-resident). ----
  for (int i = t; i < cnt; i += 256) {
    int g = glist[i];
    float2 mgi = m2[g];
    float2 lgi = l2[g];
    float th = rots[g];
    float s = __sinf(th), c = __cosf(th);
    float ivx = __expf(-2.0f * lgi.x);
    float ivy = __expf(-2.0f * lgi.y);
    sA[i] = make_float4(c * c * ivx + s * s * ivy,
                        2.0f * (c * s * (ivx - ivy)),
                        s * s * ivx + c * c * ivy, mgi.x);
  }
  __syncthreads();                                // last barrier
  int jcnt = (cnt + 15) >> 4;  // BLOCK-uniform -> dead unrolled iterations
                               // skip via scalar branch (s_cbranch)

  // ---- phase 2: eval into registers ----
  float ra[JMAX];
  float mymax = 0.0f;
#pragma unroll
  for (int j = 0; j < JMAX; ++j) {
    float a = 0.0f;
    if (j < jcnt) {
      int i = tsl + (j << 4);
      if (i < cnt) {
        float4 q0 = sA[i];
        float dx = px - q0.w, dy = py - sMy[i];
        float q = fmaf(dx, fmaf(q0.y, dy, q0.x * dx), q0.z * dy * dy);
        a = __expf(-0.5f * q);
      }
    }
    ra[j] = a;
    mymax = fmaxf(mymax, a);
  }

  // ---- tau = 10th largest of the 16 lane maxes (sound lower bound on the
  // pixel's true 10th: distinct lanes -> distinct candidates). Bitonic sort
  // across the 16-lane group; tau only gates a SUPERSET of the top-10, so
  // list-order changes upstream cannot change the final top-10. ----
  float v = mymax;
#pragma unroll
  for (int k = 2; k <= 16; k <<= 1) {
#pragma unroll
    for (int j = k >> 1; j >= 1; j >>= 1) {
      float o = __shfl_xor(v, j, 16);
      bool keepMax = (((tsl & k) == 0) == ((tsl & j) == 0));
      v = keepMax ? fmaxf(v, o) : fminf(v, o);
    }
  }
  float tau = fmaxf(__shfl(v, 9, 16), ALPHA_MIN);

  // ---- gated push via ballot compaction (no atomics, same-wave LDS) ----
  int cpx = 0;                 // group-uniform running count
  int grp = lane >> 4;
#pragma unroll
  for (int j = 0; j < JMAX; ++j) {
    if (j < jcnt) {
      bool s = ra[j] >= tau;   // implies slot valid (else ra==0 < tau)
      u64 mask = __ballot(s);
      u32 sub = (u32)((mask >> (grp * 16)) & 0xFFFFull);
      if (s) {
        int idx = cpx + __popc(sub & ((1u << tsl) - 1u));
        if (idx < SCAP)
          sbuf[pl][idx] = make_float2(ra[j], __int_as_float(glist[tsl + (j << 4)]));
      }
      cpx += __popc(sub);
    }
  }
  int scp = min(cpx, SCAP);
  int nw = min(scp, KK);

  // ---- rank-based top-10: key = (alpha_bits<<32)|~id (unique; desc key ==
  // alpha desc, id asc == exact jax.lax.top_k order). rank = #keys greater;
  // ranks distinct 0..scp-1 -> winner rank r IS the r-th extracted max.
  // Same-wave DS is in-order: sbuf reads < wbuf writes < wbuf reads. ----
#pragma unroll
  for (int c = 0; c < KEYC; ++c) {
    if ((c << 4) < scp) {      // group-uniform; usually only c=0 (scp~20)
      int i = tsl + (c << 4);
      u64 kc = 0;
      if (i < scp) {
        float2 e = sbuf[pl][i];
        kc = ((u64)__float_as_uint(e.x) << 32) | (u32)(~(u32)__float_as_int(e.y));
      }
      int rk = 0;
      for (int s2 = 0; s2 < scp; ++s2) {
        float2 e2 = sbuf[pl][s2];                 // broadcast read
        u64 ks2 = ((u64)__float_as_uint(e2.x) << 32) |
                  (u32)(~(u32)__float_as_int(e2.y));
        rk += (kc < ks2) ? 1 : 0;
      }
      if (kc != 0 && rk < KK)
        wbuf[pl][rk] = make_float2(__uint_as_float((u32)(kc >> 32)),
                                   __int_as_float((int)(~(u32)kc)));
    }
  }

  float my_alpha = 0.0f;
  int my_id = 0;
  if (tsl < nw) {              // exactly nw winners wrote ranks 0..nw-1
    float2 e = wbuf[pl][tsl];
    my_alpha = e.x;
    my_id = __float_as_int(e.y);
  }

  // ---- composite: exclusive prefix product of (1-alpha) + butterfly sum ----
  float T = 1.0f - my_alpha;           // lanes >= nw: alpha=0 -> om=1
#pragma unroll
  for (int d = 1; d < 16; d <<= 1) {
    float u = __shfl_up(T, d, 16);
    if (tsl >= d) T *= u;
  }
  float ex = __shfl_up(T, 1, 16);
  if (tsl == 0) ex = 1.0f;
  float w = my_alpha * ex;
  float cr = 0.0f, cg = 0.0f, cb = 0.0f;
  if (my_alpha > 0.0f) {
    cr = w * cols[3 * my_id + 0];
    cg = w * cols[3 * my_id + 1];
    cb = w * cols[3 * my_id + 2];
  }
#pragma unroll
  for (int d = 1; d < 16; d <<= 1) {
    cr += __shfl_xor(cr, d);
    cg += __shfl_xor(cg, d);
    cb += __shfl_xor(cb, d);
  }
  int p = y * WW + x;
  if (tsl < 3) out[3 * p + tsl] = (tsl == 0) ? cr : ((tsl == 1) ? cg : cb);
}

extern "C" void kernel_launch(void* const* d_in, const int* in_sizes, int n_in,
                              void* d_out, int out_size, void* d_ws, size_t ws_size,
                              hipStream_t stream) {
  const float* means   = (const float*)d_in[0];
  const float* rots    = (const float*)d_in[1];
  const float* lscales = (const float*)d_in[2];
  const float* cols    = (const float*)d_in[3];
  float* out = (float*)d_out;
  int nG = in_sizes[1];  // rotations: one per gaussian

  if (nG == 2048) {
    splat_kernel<2048><<<NPX / PXB, 256, 0, stream>>>(means, rots, lscales,
                                                      cols, nG, out);
  } else {
    splat_kernel<0><<<NPX / PXB, 256, 0, stream>>>(means, rots, lscales,
                                                   cols, nG, out);
  }
}

// Round 8
// 68.167 us; speedup vs baseline: 1.0675x; 1.0008x over previous
//
#include <hip/hip_runtime.h>

#define HH 128
#define WW 128
#define NPX (HH * WW)
#define KK 10
#define PXB 16        // pixels per block (4x4 tile); pixel group = 16 contiguous lanes
#define NTHR 256
#define LCAP 352      // per-tile gaussian list cap (expected ~126)
#define JMAX 22       // LCAP / 16 slots per lane
#define KEYC 6        // per-lane survivor keys (96/pixel cap, expected ~20)
#define SCAP (16 * KEYC)
#define SPAD (SCAP + 1)
#define ALPHA_MIN 5e-4f
#define RADIUS_K 3.8990f  // sqrt(2*ln(1/ALPHA_MIN))

typedef unsigned long long u64;
typedef unsigned int u32;

// R8 = EXACT R5 structure/geometry (proven 68.2us, absmax 0.0) + ONE change
// isolated from the failed R6: sbuf stores PRE-PACKED u64 keys
// (alpha_bits<<32)|~id, so the rank loop is ds_read_b64 + cmp_lt_u64 + add
// instead of rebuilding the key from float2 each iteration. Bit-identical
// key values and ordering to R5. Plus R7's free hardening (wbuf zero-init,
// clamped gathers) which is a no-op on valid data.
//
// One block = one 4x4-pixel tile; 4 waves; each pixel owned by 16 contiguous
// lanes of one wave -> all post-filter steps are wave-synchronous.
template <int NGC>
__global__ __launch_bounds__(NTHR) void splat_kernel(
    const float* __restrict__ means, const float* __restrict__ rots,
    const float* __restrict__ lscales, const float* __restrict__ cols,
    int nG_rt, float* __restrict__ out) {
  const int nG = NGC > 0 ? NGC : nG_rt;
  __shared__ float4 sA[LCAP];           // (a, 2b, c, mean_x)
  __shared__ float  sMy[LCAP];
  __shared__ int    glist[LCAP];
  __shared__ u64    sbuf[PXB][SPAD];    // packed survivor keys
  __shared__ u64    wbuf[PXB][KK];      // winners by rank (packed)
  __shared__ int    lcnt;

  int t = threadIdx.x;
  int lane = t & 63;
  int pl  = t >> 4;   // pixel within tile (wave w owns pixels 4w..4w+3)
  int tsl = t & 15;   // lane within pixel group
  int tile = blockIdx.x;
  int x0 = (tile & 31) << 2, y0 = (tile >> 5) << 2;
  int x = x0 | (pl & 3), y = y0 | (pl >> 2);
  float px = (float)x + 0.5f, py = (float)y + 0.5f;

  if (t == 0) lcnt = 0;
  __syncthreads();

  // ---- phase 1a: conservative bbox filter from RAW inputs, register-
  // prefetched; ballot-aggregated compaction writes only glist/sMy (no trig
  // in the divergent hit path). alpha >= ALPHA_MIN implies |d| <=
  // RADIUS_K*s_max; circle-vs-rect with fp32 margin never drops one. ----
  const float2* m2 = (const float2*)means;
  const float2* l2 = (const float2*)lscales;
  float rx0 = (float)x0 + 0.5f, rx1 = (float)x0 + 3.5f;
  float ry0 = (float)y0 + 0.5f, ry1 = (float)y0 + 3.5f;
  if (NGC > 0) {
    constexpr int FR = ((NGC > 0 ? NGC : 1) + NTHR - 1) / NTHR;
    float2 mg[FR], lg[FR];
#pragma unroll
    for (int j = 0; j < FR; ++j) {
      int g = t + j * NTHR;
      bool v = g < NGC;
      mg[j] = v ? m2[g] : make_float2(-1e30f, -1e30f);
      lg[j] = v ? l2[g] : make_float2(0.0f, 0.0f);
    }
#pragma unroll
    for (int j = 0; j < FR; ++j) {
      float smx = __expf(fmaxf(lg[j].x, lg[j].y));
      float r = fmaf(RADIUS_K * 1.01f, smx, 0.05f);
      float cx = fminf(fmaxf(mg[j].x, rx0), rx1) - mg[j].x;
      float cy = fminf(fmaxf(mg[j].y, ry0), ry1) - mg[j].y;
      bool hit = (cx * cx + cy * cy <= r * r);
      u64 mask = __ballot(hit);
      if (mask) {                                 // wave-uniform
        int leader = __ffsll((unsigned long long)mask) - 1;
        int base;
        if (lane == leader) base = atomicAdd(&lcnt, __popcll(mask));
        base = __shfl(base, leader);
        if (hit) {
          int idx = base + __popcll(mask & ((1ull << lane) - 1ull));
          if (idx >= 0 && idx < LCAP) {
            sMy[idx] = mg[j].y;
            glist[idx] = t + j * NTHR;
          }
        }
      }
    }
  } else {
    for (int g = t; g < nG; g += NTHR) {
      float2 mgj = m2[g];
      float2 lgj = l2[g];
      float smx = __expf(fmaxf(lgj.x, lgj.y));
      float r = fmaf(RADIUS_K * 1.01f, smx, 0.05f);
      float cx = fminf(fmaxf(mgj.x, rx0), rx1) - mgj.x;
      float cy = fminf(fmaxf(mgj.y, ry0), ry1) - mgj.y;
      bool hit = (cx * cx + cy * cy <= r * r);
      u64 mask = __ballot(hit);
      if (mask) {
        int leader = __ffsll((unsigned long long)mask) - 1;
        int base;
        if (lane == leader) base = atomicAdd(&lcnt, __popcll(mask));
        base = __shfl(base, leader);
        if (hit) {
          int idx = base + __popcll(mask & ((1ull << lane) - 1ull));
          if (idx >= 0 && idx < LCAP) {
            sMy[idx] = mgj.y;
            glist[idx] = g;
          }
        }
      }
    }
  }
  __syncthreads();
  int cnt = min(lcnt, LCAP);

  // ---- phase 1b: dense per-survivor param build (~cnt=126 threads, one
  // round, full lane utilization; gathered loads are L2-resident). Index
  // clamped: no-op on valid data, removes any possible fault path. ----
  for (int i = t; i < cnt; i += NTHR) {
    int g = min(max(glist[i], 0), nG - 1);
    float2 mgi = m2[g];
    float2 lgi = l2[g];
    float th = rots[g];
    float s = __sinf(th), c = __cosf(th);
    float ivx = __expf(-2.0f * lgi.x);
    float ivy = __expf(-2.0f * lgi.y);
    sA[i] = make_float4(c * c * ivx + s * s * ivy,
                        2.0f * (c * s * (ivx - ivy)),
                        s * s * ivx + c * c * ivy, mgi.x);
  }
  __syncthreads();                                // last barrier
  int jcnt = (cnt + 15) >> 4;  // BLOCK-uniform -> dead unrolled iterations
                               // skip via scalar branch (s_cbranch)

  // ---- phase 2: eval into registers ----
  float ra[JMAX];
  float mymax = 0.0f;
#pragma unroll
  for (int j = 0; j < JMAX; ++j) {
    float a = 0.0f;
    if (j < jcnt) {
      int i = tsl + (j << 4);
      if (i < cnt) {
        float4 q0 = sA[i];
        float dx = px - q0.w, dy = py - sMy[i];
        float q = fmaf(dx, fmaf(q0.y, dy, q0.x * dx), q0.z * dy * dy);
        a = __expf(-0.5f * q);
      }
    }
    ra[j] = a;
    mymax = fmaxf(mymax, a);
  }

  // ---- tau = 10th largest of the 16 lane maxes (sound lower bound on the
  // pixel's true 10th: the 16 lane maxes are alphas of 16 DISTINCT
  // gaussians). Bitonic sort across the 16-lane group; ties kept via >=
  // downstream. ----
  float v = mymax;
#pragma unroll
  for (int k = 2; k <= 16; k <<= 1) {
#pragma unroll
    for (int j = k >> 1; j >= 1; j >>= 1) {
      float o = __shfl_xor(v, j, 16);
      bool keepMax = (((tsl & k) == 0) == ((tsl & j) == 0));
      v = keepMax ? fmaxf(v, o) : fminf(v, o);
    }
  }
  float tau = fmaxf(__shfl(v, 9, 16), ALPHA_MIN);

  // ---- gated push via ballot compaction (no atomics, same-wave LDS).
  // Key packed ONCE: (alpha_bits<<32)|~id. Key desc == alpha desc, id asc
  // == exact jax.lax.top_k order. Keys unique, never 0 (alpha >= ALPHA_MIN
  // -> hi word nonzero). Same key bits/order as R5. ----
  int cpx = 0;                 // group-uniform running count
  int grp = lane >> 4;
#pragma unroll
  for (int j = 0; j < JMAX; ++j) {
    if (j < jcnt) {
      bool s = ra[j] >= tau;   // implies slot valid (else ra==0 < tau)
      u64 mask = __ballot(s);
      u32 sub = (u32)((mask >> (grp * 16)) & 0xFFFFull);
      if (s) {
        int idx = cpx + __popc(sub & ((1u << tsl) - 1u));
        if (idx < SCAP)
          sbuf[pl][idx] = ((u64)__float_as_uint(ra[j]) << 32) |
                          (u32)(~(u32)glist[tsl + (j << 4)]);
      }
      cpx += __popc(sub);
    }
  }
  int scp = min(cpx, SCAP);
  int nw = min(scp, KK);

  // ---- rank-based top-10 over pre-packed keys: rank = #keys greater;
  // keys unique -> ranks distinct 0..scp-1 -> winner rank r IS the r-th
  // extracted max. wbuf ZERO-INITed: a missed rank reads key 0 -> inert
  // lane, never garbage. Same-wave DS is in-order: init < sbuf reads <
  // wbuf writes < wbuf reads in program order. ----
  if (tsl < KK) wbuf[pl][tsl] = 0;
#pragma unroll
  for (int c = 0; c < KEYC; ++c) {
    if ((c << 4) < scp) {      // group-uniform; usually only c=0 (scp~20)
      int i = tsl + (c << 4);
      u64 kc = (i < scp) ? sbuf[pl][i] : 0;
      int rk = 0;
      for (int s2 = 0; s2 < scp; ++s2)
        rk += (kc < sbuf[pl][s2]) ? 1 : 0;
      if (kc != 0 && rk < KK) wbuf[pl][rk] = kc;
    }
  }

  float my_alpha = 0.0f;
  int my_id = 0;
  if (tsl < nw) {              // nw winners wrote ranks 0..nw-1
    u64 k = wbuf[pl][tsl];
    my_alpha = __uint_as_float((u32)(k >> 32));
    my_id = (int)(~(u32)k);
  }

  // ---- composite: exclusive prefix product of (1-alpha) + butterfly sum ----
  float T = 1.0f - my_alpha;           // inert lanes: alpha=0 -> om=1
#pragma unroll
  for (int d = 1; d < 16; d <<= 1) {
    float u = __shfl_up(T, d, 16);
    if (tsl >= d) T *= u;
  }
  float ex = __shfl_up(T, 1, 16);
  if (tsl == 0) ex = 1.0f;
  float w = my_alpha * ex;
  float cr = 0.0f, cg = 0.0f, cb = 0.0f;
  if (my_alpha > 0.0f && (u32)my_id < (u32)nG) {   // clamp: no-op on valid data
    cr = w * cols[3 * my_id + 0];
    cg = w * cols[3 * my_id + 1];
    cb = w * cols[3 * my_id + 2];
  }
#pragma unroll
  for (int d = 1; d < 16; d <<= 1) {
    cr += __shfl_xor(cr, d);
    cg += __shfl_xor(cg, d);
    cb += __shfl_xor(cb, d);
  }
  int p = y * WW + x;
  if (tsl < 3) out[3 * p + tsl] = (tsl == 0) ? cr : ((tsl == 1) ? cg : cb);
}

extern "C" void kernel_launch(void* const* d_in, const int* in_sizes, int n_in,
                              void* d_out, int out_size, void* d_ws, size_t ws_size,
                              hipStream_t stream) {
  const float* means   = (const float*)d_in[0];
  const float* rots    = (const float*)d_in[1];
  const float* lscales = (const float*)d_in[2];
  const float* cols    = (const float*)d_in[3];
  float* out = (float*)d_out;
  int nG = in_sizes[1];  // rotations: one per gaussian

  if (nG == 2048) {
    splat_kernel<2048><<<NPX / PXB, NTHR, 0, stream>>>(means, rots, lscales,
                                                       cols, nG, out);
  } else {
    splat_kernel<0><<<NPX / PXB, NTHR, 0, stream>>>(means, rots, lscales,
                                                    cols, nG, out);
  }
}